// Round 11
// baseline (115.286 us; speedup 1.0000x reference)
//
#include <hip/hip_runtime.h>
#include <hip/hip_bf16.h>

// HSA prefill R11 = R10 + S-split 2 for occupancy.
// R10 post-mortem: grid 512 = 2 wg/CU = 2 waves/SIMD -- occupancy was
// GRID-limited, so barrier drains (~350 cyc residual K-load latency per iter)
// had nothing to overlap with. Split the 16 s-blocks across 2 wgs:
// grid 1024 = 4 wg/CU = 4 waves/SIMD; partials are exactly additive
// (per-block softmax) and combined via fp32 atomicAdd into memset-zeroed out.
// LDS 37.9KB x4 = 151.6KB <= 160 OK; launch_bounds(256,4) -> VGPR cap 128
// (R10 measured 84 -> no spill).
// Everything else unchanged from R10 (non-redundant scores, deferred
// normalization single barrier, V via global_load_lds dbuf, K reg-prefetch).

namespace {

constexpr int kLq = 256, kHQ = 32, kH = 2, kG = 16, kD = 128, kS = 16;
constexpr int kNB = 64;                    // Lkv/BS: distinct blocks per head
constexpr int kSB = 8;                     // s-blocks per wg (S-split 2)
constexpr float kScaleLog2e = 0.08838834764831845f * 1.4426950408889634f;

constexpr int kKPackN = kH * kNB * 16 * 64;  // uint4 elems per array (2 MB)
constexpr int kPStr   = 72;                  // P row stride (shorts), 16B-mult
constexpr int kSStr   = 136;                 // pack LDS row stride (shorts)

typedef short s16x8 __attribute__((ext_vector_type(8)));
typedef float f32x4 __attribute__((ext_vector_type(4)));

union U32BF2 { unsigned int u; __hip_bfloat162 h; };
union FragU  { uint4 u; s16x8 v; };

static __device__ inline unsigned int pk_bf16(float a, float b) {
    U32BF2 z; z.h = __float22bfloat162_rn(make_float2(a, b));
    return z.u;
}

// ---------------- pack kernel: 512 wgs, each handles half a block ----------
// K_packed idx = ((h*64+blk)*16 + t*4+st)*64 + lane (lane = quad*16+n)
//   holds K[u = blk*64 + t*16 + n][h][d = st*32 + quad*8 + j]
// V_packed idx = ((h*64+blk)*16 + dt*2+st)*64 + lane
//   holds V[u = blk*64 + st*32 + quad*8 + j][h][d = dt*16 + n]
__global__ __launch_bounds__(256)
void pack_kv(const float* __restrict__ k, const float* __restrict__ v,
             uint4* __restrict__ kp, uint4* __restrict__ vp)
{
    __shared__ unsigned short S_s[32 * kSStr];   // 8.7 KB bf16 [u_loc][d]

    const int bid  = blockIdx.x;                 // 0..511
    const int isV  = bid & 1;
    const int half = (bid >> 1) & 1;
    const int blk  = (bid >> 2) & 63;
    const int h    = bid >> 8;
    const int t    = threadIdx.x;
    const int lane = t & 63, n = lane & 15, quad = lane >> 4;
    const int wv   = t >> 6;                     // 0..3

    {   // coalesced load 32 rows x 128 fp32 -> bf16 LDS
        const float* src = (isV ? v : k) +
            ((size_t)(blk * 64 + half * 32) * kH + h) * kD;
        const int r0 = t >> 5, c4 = (t & 31) << 2;
        #pragma unroll
        for (int p = 0; p < 4; ++p) {
            const int r = p * 8 + r0;
            const float4 f = *(const float4*)(src + (size_t)r * (kH * kD) + c4);
            *(unsigned int*)&S_s[r * kSStr + c4]     = pk_bf16(f.x, f.y);
            *(unsigned int*)&S_s[r * kSStr + c4 + 2] = pk_bf16(f.z, f.w);
        }
    }
    __syncthreads();

    const size_t obase = (size_t)(h * 64 + blk) * 16 * 64;
    if (!isV) {
        #pragma unroll
        for (int rep = 0; rep < 2; ++rep) {
            const int cl    = wv * 2 + rep;      // 0..7
            const int t_loc = cl >> 2, st = cl & 3;
            const int c     = (2 * half + t_loc) * 4 + st;
            const int u_loc = t_loc * 16 + n;
            kp[obase + (size_t)c * 64 + lane] =
                *(const uint4*)&S_s[u_loc * kSStr + st * 32 + quad * 8];
        }
    } else {
        #pragma unroll
        for (int rep = 0; rep < 2; ++rep) {
            const int dt = wv * 2 + rep;         // 0..7
            const int c  = dt * 2 + half;
            const int d  = dt * 16 + n;
            unsigned short s[8];
            #pragma unroll
            for (int j = 0; j < 8; ++j) s[j] = S_s[(quad * 8 + j) * kSStr + d];
            uint4 val;
            val.x = s[0] | ((unsigned)s[1] << 16);
            val.y = s[2] | ((unsigned)s[3] << 16);
            val.z = s[4] | ((unsigned)s[5] << 16);
            val.w = s[6] | ((unsigned)s[7] << 16);
            vp[obase + (size_t)c * 64 + lane] = val;
        }
    }
}

// ---------------- main kernel --------------------------------------------
__global__ __launch_bounds__(256, 4)
void hsa_main(const float* __restrict__ q, const float* __restrict__ w,
              const int* __restrict__ bidx, const uint4* __restrict__ kp,
              const uint4* __restrict__ vp, float* __restrict__ out)
{
    __shared__ __align__(16) uint4 vbuf[2][16 * 64];               // 32 KB
    __shared__ __align__(16) unsigned short P_s[2][kG * kPStr];    // 4.6 KB
    __shared__ __align__(16) float psum[2][kG][4];                 // 512 B

    const int bid   = blockIdx.x;                // 0..1023
    const int l     = bid >> 2;
    const int h     = (bid >> 1) & 1;
    const int split = bid & 1;
    const int tid   = threadIdx.x;
    const int wave  = tid >> 6;
    const int lane  = tid & 63;
    const int n     = lane & 15;
    const int quad  = lane >> 4;

    // Q B-frags: lane g=n, k = st*32 + quad*8 + j
    s16x8 qf[4];
    {
        const float* qb = q + ((size_t)l * kHQ + h * kG + n) * kD + quad * 8;
        #pragma unroll
        for (int st = 0; st < 4; ++st) {
            const float4 f0 = *(const float4*)(qb + st * 32);
            const float4 f1 = *(const float4*)(qb + st * 32 + 4);
            union { s16x8 v; unsigned int u[4]; } z;
            z.u[0] = pk_bf16(f0.x, f0.y); z.u[1] = pk_bf16(f0.z, f0.w);
            z.u[2] = pk_bf16(f1.x, f1.y); z.u[3] = pk_bf16(f1.z, f1.w);
            qf[st] = z.v;
        }
    }

    // this wg's 8 s-slots: block bases (uniform) + per-lane weights
    int   base_[kSB];
    float wval[kSB];
    #pragma unroll
    for (int i = 0; i < 2; ++i) {
        const int4   b4 = *(const int4*)(bidx + (size_t)(l * kH + h) * kS + split * kSB + i * 4);
        const float4 w4 = *(const float4*)(w + ((size_t)l * kHQ + h * kG + n) * kS + split * kSB + i * 4);
        const int   bb[4] = {b4.x, b4.y, b4.z, b4.w};
        const float ww[4] = {w4.x, w4.y, w4.z, w4.w};
        #pragma unroll
        for (int jj = 0; jj < 4; ++jj) {
            wval[i * 4 + jj]  = (bb[jj] < 0) ? 0.f : ww[jj];
            base_[i * 4 + jj] = (h * kNB + max(bb[jj], 0)) * 1024;  // uint4 idx
        }
    }

    // each wave stages V frags [wave*4, wave*4+4) of the given block
    #define STAGE_V(js_, b_)                                                   \
        {                                                                      \
            const uint4* gp = vp + base_[(js_)] + (wave * 4) * 64 + lane;      \
            auto* lp = (__attribute__((address_space(3))) uint4*)              \
                           &vbuf[(b_)][(wave * 4) * 64];                       \
            _Pragma("unroll")                                                  \
            for (int i_ = 0; i_ < 4; ++i_)                                     \
                __builtin_amdgcn_global_load_lds(                              \
                    (const __attribute__((address_space(1))) void*)(gp + i_ * 64), \
                    (__attribute__((address_space(3))) void*)(lp + i_ * 64),   \
                    16, 0, 0);                                                 \
        }

    // prologue: V[0] staging + K[0] frags in flight (drained at C(0))
    STAGE_V(0, 0);
    FragU kreg[4];
    #pragma unroll
    for (int st = 0; st < 4; ++st)
        kreg[st].u = kp[base_[0] + (wave * 4 + st) * 64 + lane];
    __builtin_amdgcn_sched_barrier(0);

    f32x4 oacc0 = {0.f, 0.f, 0.f, 0.f};   // d-tile 2*wave
    f32x4 oacc1 = {0.f, 0.f, 0.f, 0.f};   // d-tile 2*wave+1

    #pragma unroll
    for (int js = 0; js < kSB; ++js) {
        const int cur = js & 1;

        // ---- scores: wave owns u-tile = wave (u = wave*16 + quad*4 + r) ----
        f32x4 sc = {0.f, 0.f, 0.f, 0.f};
        #pragma unroll
        for (int st = 0; st < 4; ++st)
            sc = __builtin_amdgcn_mfma_f32_16x16x32_bf16(kreg[st].v, qf[st], sc, 0, 0, 0);

        // prefetch next block's K frags (kreg dead after MFMAs above)
        if (js < kSB - 1) {
            #pragma unroll
            for (int st = 0; st < 4; ++st)
                kreg[st].u = kp[base_[js + 1] + (wave * 4 + st) * 64 + lane];
        }
        __builtin_amdgcn_sched_barrier(0);

        // ---- exp (4 values/lane) + wave-partial denominator ----
        float part = 0.f;
        #pragma unroll
        for (int r = 0; r < 4; ++r) {
            sc[r] = exp2f(sc[r] * kScaleLog2e);
            part += sc[r];
        }
        part += __shfl_xor(part, 16);
        part += __shfl_xor(part, 32);      // all quads of column n share partial
        if (quad == 0) psum[cur][n][wave] = part;

        // ---- UNNORMALIZED P -> shared LDS (B-frag order) ----
        const unsigned long long pq =
            ((unsigned long long)pk_bf16(sc[2], sc[3]) << 32) | pk_bf16(sc[0], sc[1]);
        *(unsigned long long*)&P_s[cur][n * kPStr + wave * 16 + quad * 4] = pq;

        __syncthreads();                   // C(js): psum+P visible; V[js] DMA drained

        // ---- denominator + per-lane coef (lane n owns output column g=n) ----
        const float4 ps  = *(const float4*)&psum[cur][n][0];
        const float coef = wval[js] / (ps.x + ps.y + ps.z + ps.w);
        const s16x8 bf0 = *(const s16x8*)&P_s[cur][n * kPStr + quad * 8];
        const s16x8 bf1 = *(const s16x8*)&P_s[cur][n * kPStr + 32 + quad * 8];

        // ---- issue V[js+1] staging (drained by C(js+1), a full phase away) ----
        if (js < kSB - 1) { STAGE_V(js + 1, cur ^ 1); }
        __builtin_amdgcn_sched_barrier(0);

        // ---- PV into fresh pacc, then oacc += coef * pacc ----
        const f32x4 zero = {0.f, 0.f, 0.f, 0.f};
        const s16x8 a0 = *(const s16x8*)&vbuf[cur][(wave * 4 + 0) * 64 + lane];
        const s16x8 a1 = *(const s16x8*)&vbuf[cur][(wave * 4 + 1) * 64 + lane];
        const s16x8 a2 = *(const s16x8*)&vbuf[cur][(wave * 4 + 2) * 64 + lane];
        const s16x8 a3 = *(const s16x8*)&vbuf[cur][(wave * 4 + 3) * 64 + lane];
        f32x4 p0 = __builtin_amdgcn_mfma_f32_16x16x32_bf16(a0, bf0, zero, 0, 0, 0);
        p0       = __builtin_amdgcn_mfma_f32_16x16x32_bf16(a1, bf1, p0,   0, 0, 0);
        f32x4 p1 = __builtin_amdgcn_mfma_f32_16x16x32_bf16(a2, bf0, zero, 0, 0, 0);
        p1       = __builtin_amdgcn_mfma_f32_16x16x32_bf16(a3, bf1, p1,   0, 0, 0);
        #pragma unroll
        for (int r = 0; r < 4; ++r) {
            oacc0[r] = fmaf(coef, p0[r], oacc0[r]);
            oacc1[r] = fmaf(coef, p1[r], oacc1[r]);
        }
    }
    #undef STAGE_V

    // ---- epilogue: atomic-accumulate split partial into out ----
    {
        float* ob = out + ((size_t)l * kHQ + h * kG + n) * kD;
        const int d0 = wave * 32 + quad * 4;
        #pragma unroll
        for (int i = 0; i < 4; ++i) {
            atomicAdd(ob + d0 + i,      oacc0[i]);
            atomicAdd(ob + d0 + 16 + i, oacc1[i]);
        }
    }
}

} // namespace

extern "C" void kernel_launch(void* const* d_in, const int* in_sizes, int n_in,
                              void* d_out, int out_size, void* d_ws, size_t ws_size,
                              hipStream_t stream)
{
    const float* q    = (const float*)d_in[0];
    const float* k    = (const float*)d_in[1];
    const float* v    = (const float*)d_in[2];
    const float* w    = (const float*)d_in[3];
    const int*   bidx = (const int*)d_in[4];
    float* out = (float*)d_out;

    uint4* kp = (uint4*)d_ws;                                   // 2 MB
    uint4* vp = (uint4*)((char*)d_ws + (size_t)kKPackN * 16);   // 2 MB

    hipMemsetAsync(out, 0, (size_t)out_size * sizeof(float), stream);
    pack_kv<<<dim3(512), dim3(256), 0, stream>>>(k, v, kp, vp);
    hsa_main<<<dim3(kLq * kH * 2), dim3(256), 0, stream>>>(q, w, bidx, kp, vp, out);
}

// Round 12
// 93.831 us; speedup vs baseline: 1.2287x; 1.2287x over previous
//
#include <hip/hip_runtime.h>
#include <hip/hip_bf16.h>

// HSA prefill R12: two-team 512-thread wg (revert R11's S-split).
// R11 post-mortem: S-split regressed (atomics + extra dispatch + duplicated
// prologues + less work per barrier). R12 keeps grid 512 and instead doubles
// SIMD occupancy with 512-thr wgs: 2 wg/CU x 8 waves = 4 waves/SIMD (2x R10).
// Waves form 2 teams; per iteration jp (8 iters) team t runs a full R10-style
// block step on s = 2*jp+t (own vbuf/P/psum slots), one wg barrier per iter
// (8 barriers vs R10's 16). ALL prefetch (K regs + V DMA) is issued AFTER the
// barrier: the barrier drains only DMA issued a full phase earlier (~free);
// K loads are drained by per-wave waitcnt at next iter's MFMAs (covered by
// PV), never by a wg-wide vmcnt(0).
// Epilogue: team 1 parks partial O in LDS (vbuf reuse), team 0 adds + direct
// coalesced stores. No atomics, no memset, 2 dispatches total.
// LDS 74.2 KB x 2 wg = 148.4 <= 160; launch_bounds(512,4) -> VGPR cap 128.

namespace {

constexpr int kLq = 256, kHQ = 32, kH = 2, kG = 16, kD = 128, kS = 16;
constexpr int kNB = 64;                    // Lkv/BS: distinct blocks per head
constexpr float kScaleLog2e = 0.08838834764831845f * 1.4426950408889634f;

constexpr int kKPackN = kH * kNB * 16 * 64;  // uint4 elems per array (2 MB)
constexpr int kPStr   = 72;                  // P row stride (shorts), 16B-mult
constexpr int kSStr   = 136;                 // pack LDS row stride (shorts)

typedef short s16x8 __attribute__((ext_vector_type(8)));
typedef float f32x4 __attribute__((ext_vector_type(4)));

union U32BF2 { unsigned int u; __hip_bfloat162 h; };
union FragU  { uint4 u; s16x8 v; };

static __device__ inline unsigned int pk_bf16(float a, float b) {
    U32BF2 z; z.h = __float22bfloat162_rn(make_float2(a, b));
    return z.u;
}

// ---------------- pack kernel: 512 wgs, each handles half a block ----------
// K_packed idx = ((h*64+blk)*16 + t*4+st)*64 + lane (lane = quad*16+n)
//   holds K[u = blk*64 + t*16 + n][h][d = st*32 + quad*8 + j]
// V_packed idx = ((h*64+blk)*16 + dt*2+st)*64 + lane
//   holds V[u = blk*64 + st*32 + quad*8 + j][h][d = dt*16 + n]
__global__ __launch_bounds__(256)
void pack_kv(const float* __restrict__ k, const float* __restrict__ v,
             uint4* __restrict__ kp, uint4* __restrict__ vp)
{
    __shared__ unsigned short S_s[32 * kSStr];   // 8.7 KB bf16 [u_loc][d]

    const int bid  = blockIdx.x;                 // 0..511
    const int isV  = bid & 1;
    const int half = (bid >> 1) & 1;
    const int blk  = (bid >> 2) & 63;
    const int h    = bid >> 8;
    const int t    = threadIdx.x;
    const int lane = t & 63, n = lane & 15, quad = lane >> 4;
    const int wv   = t >> 6;                     // 0..3

    {   // coalesced load 32 rows x 128 fp32 -> bf16 LDS
        const float* src = (isV ? v : k) +
            ((size_t)(blk * 64 + half * 32) * kH + h) * kD;
        const int r0 = t >> 5, c4 = (t & 31) << 2;
        #pragma unroll
        for (int p = 0; p < 4; ++p) {
            const int r = p * 8 + r0;
            const float4 f = *(const float4*)(src + (size_t)r * (kH * kD) + c4);
            *(unsigned int*)&S_s[r * kSStr + c4]     = pk_bf16(f.x, f.y);
            *(unsigned int*)&S_s[r * kSStr + c4 + 2] = pk_bf16(f.z, f.w);
        }
    }
    __syncthreads();

    const size_t obase = (size_t)(h * 64 + blk) * 16 * 64;
    if (!isV) {
        #pragma unroll
        for (int rep = 0; rep < 2; ++rep) {
            const int cl    = wv * 2 + rep;      // 0..7
            const int t_loc = cl >> 2, st = cl & 3;
            const int c     = (2 * half + t_loc) * 4 + st;
            const int u_loc = t_loc * 16 + n;
            kp[obase + (size_t)c * 64 + lane] =
                *(const uint4*)&S_s[u_loc * kSStr + st * 32 + quad * 8];
        }
    } else {
        #pragma unroll
        for (int rep = 0; rep < 2; ++rep) {
            const int dt = wv * 2 + rep;         // 0..7
            const int c  = dt * 2 + half;
            const int d  = dt * 16 + n;
            unsigned short s[8];
            #pragma unroll
            for (int j = 0; j < 8; ++j) s[j] = S_s[(quad * 8 + j) * kSStr + d];
            uint4 val;
            val.x = s[0] | ((unsigned)s[1] << 16);
            val.y = s[2] | ((unsigned)s[3] << 16);
            val.z = s[4] | ((unsigned)s[5] << 16);
            val.w = s[6] | ((unsigned)s[7] << 16);
            vp[obase + (size_t)c * 64 + lane] = val;
        }
    }
}

// ---------------- main kernel --------------------------------------------
__global__ __launch_bounds__(512, 4)
void hsa_main(const float* __restrict__ q, const float* __restrict__ w,
              const int* __restrict__ bidx, const uint4* __restrict__ kp,
              const uint4* __restrict__ vp, float* __restrict__ out)
{
    __shared__ __align__(16) uint4 vbuf[2][2][16 * 64];              // 64 KB
    __shared__ __align__(16) unsigned short P_s[2][2][kG * kPStr];   // 9.2 KB
    __shared__ __align__(16) float psum[2][2][kG][4];                // 1 KB

    const int bid  = blockIdx.x;                 // 0..511
    const int l    = bid >> 1;
    const int h    = bid & 1;
    const int tid  = threadIdx.x;
    const int wave = tid >> 6;
    const int team = wave >> 2;                  // 0,1
    const int tw   = wave & 3;                   // wave-in-team
    const int lane = tid & 63;
    const int n    = lane & 15;
    const int quad = lane >> 4;

    // Q B-frags: lane g=n, k = st*32 + quad*8 + j
    s16x8 qf[4];
    {
        const float* qb = q + ((size_t)l * kHQ + h * kG + n) * kD + quad * 8;
        #pragma unroll
        for (int st = 0; st < 4; ++st) {
            const float4 f0 = *(const float4*)(qb + st * 32);
            const float4 f1 = *(const float4*)(qb + st * 32 + 4);
            union { s16x8 v; unsigned int u[4]; } z;
            z.u[0] = pk_bf16(f0.x, f0.y); z.u[1] = pk_bf16(f0.z, f0.w);
            z.u[2] = pk_bf16(f1.x, f1.y); z.u[3] = pk_bf16(f1.z, f1.w);
            qf[st] = z.v;
        }
    }

    // this team's 8 s-slots (s = 2*jp + team): bases (wave-uniform) + weights
    int   base8[8];
    float wval8[8];
    #pragma unroll
    for (int j = 0; j < 8; ++j) {
        const int s  = 2 * j + team;
        const int bi = bidx[(size_t)(l * kH + h) * kS + s];
        wval8[j] = (bi < 0) ? 0.f : w[((size_t)l * kHQ + h * kG + n) * kS + s];
        base8[j] = (h * kNB + max(bi, 0)) * 1024;   // uint4 idx
    }

    // wave stages V frags [tw*4, tw*4+4) of its team's block for pair jp_
    #define STAGE_V(jp_, b_)                                                   \
        {                                                                      \
            const uint4* gp = vp + base8[(jp_)] + (tw * 4) * 64 + lane;        \
            auto* lp = (__attribute__((address_space(3))) uint4*)              \
                           &vbuf[(b_)][team][(tw * 4) * 64];                   \
            _Pragma("unroll")                                                  \
            for (int i_ = 0; i_ < 4; ++i_)                                     \
                __builtin_amdgcn_global_load_lds(                              \
                    (const __attribute__((address_space(1))) void*)(gp + i_ * 64), \
                    (__attribute__((address_space(3))) void*)(lp + i_ * 64),   \
                    16, 0, 0);                                                 \
        }

    // prologue: V(pair 0) DMA + K(pair 0) register frags in flight
    STAGE_V(0, 0);
    FragU kreg[4];
    #pragma unroll
    for (int st = 0; st < 4; ++st)
        kreg[st].u = kp[base8[0] + (tw * 4 + st) * 64 + lane];
    __builtin_amdgcn_sched_barrier(0);

    f32x4 oacc0 = {0.f, 0.f, 0.f, 0.f};   // d-tile 2*tw   (team partial)
    f32x4 oacc1 = {0.f, 0.f, 0.f, 0.f};   // d-tile 2*tw+1 (team partial)

    #pragma unroll
    for (int jp = 0; jp < 8; ++jp) {
        const int cur = jp & 1;

        // ---- scores: wave owns u-tile tw of its team's block ----
        f32x4 sc = {0.f, 0.f, 0.f, 0.f};
        #pragma unroll
        for (int st = 0; st < 4; ++st)
            sc = __builtin_amdgcn_mfma_f32_16x16x32_bf16(kreg[st].v, qf[st], sc, 0, 0, 0);

        // ---- exp (4/lane) + wave-partial denominator ----
        float part = 0.f;
        #pragma unroll
        for (int r = 0; r < 4; ++r) {
            sc[r] = exp2f(sc[r] * kScaleLog2e);
            part += sc[r];
        }
        part += __shfl_xor(part, 16);
        part += __shfl_xor(part, 32);
        if (quad == 0) psum[cur][team][n][tw] = part;

        // ---- UNNORMALIZED P -> team LDS slot (B-frag order) ----
        const unsigned long long pq =
            ((unsigned long long)pk_bf16(sc[2], sc[3]) << 32) | pk_bf16(sc[0], sc[1]);
        *(unsigned long long*)&P_s[cur][team][n * kPStr + tw * 16 + quad * 4] = pq;

        // barrier: psum/P visible. vmcnt(0) drain only covers V DMA issued a
        // FULL phase ago (prologue or jp-1 post-barrier) -> ~free.
        __syncthreads();

        // ---- issue next pair's prefetch AFTER the barrier ----
        if (jp < 7) {
            #pragma unroll
            for (int st = 0; st < 4; ++st)
                kreg[st].u = kp[base8[jp + 1] + (tw * 4 + st) * 64 + lane];
            STAGE_V(jp + 1, cur ^ 1);
        }
        __builtin_amdgcn_sched_barrier(0);

        // ---- denominator + per-lane coef (lane n owns output column g=n) ----
        const float4 ps  = *(const float4*)&psum[cur][team][n][0];
        const float coef = wval8[jp] / (ps.x + ps.y + ps.z + ps.w);
        const s16x8 bf0 = *(const s16x8*)&P_s[cur][team][n * kPStr + quad * 8];
        const s16x8 bf1 = *(const s16x8*)&P_s[cur][team][n * kPStr + 32 + quad * 8];

        // ---- PV into fresh pacc, then oacc += coef * pacc ----
        const f32x4 zero = {0.f, 0.f, 0.f, 0.f};
        const s16x8 a0 = *(const s16x8*)&vbuf[cur][team][(tw * 4 + 0) * 64 + lane];
        const s16x8 a1 = *(const s16x8*)&vbuf[cur][team][(tw * 4 + 1) * 64 + lane];
        const s16x8 a2 = *(const s16x8*)&vbuf[cur][team][(tw * 4 + 2) * 64 + lane];
        const s16x8 a3 = *(const s16x8*)&vbuf[cur][team][(tw * 4 + 3) * 64 + lane];
        f32x4 p0 = __builtin_amdgcn_mfma_f32_16x16x32_bf16(a0, bf0, zero, 0, 0, 0);
        p0       = __builtin_amdgcn_mfma_f32_16x16x32_bf16(a1, bf1, p0,   0, 0, 0);
        f32x4 p1 = __builtin_amdgcn_mfma_f32_16x16x32_bf16(a2, bf0, zero, 0, 0, 0);
        p1       = __builtin_amdgcn_mfma_f32_16x16x32_bf16(a3, bf1, p1,   0, 0, 0);
        #pragma unroll
        for (int r = 0; r < 4; ++r) {
            oacc0[r] = fmaf(coef, p0[r], oacc0[r]);
            oacc1[r] = fmaf(coef, p1[r], oacc1[r]);
        }
    }
    #undef STAGE_V

    // ---- combine the two teams' partials via LDS (vbuf reused), store ----
    __syncthreads();                       // all PV reads of vbuf done
    {
        float* Ored = (float*)&vbuf[0][0][0];   // [d=128][n=16] floats, 8 KB
        if (team == 1) {
            #pragma unroll
            for (int r = 0; r < 4; ++r) {
                Ored[((tw * 2 + 0) * 16 + quad * 4 + r) * 16 + n] = oacc0[r];
                Ored[((tw * 2 + 1) * 16 + quad * 4 + r) * 16 + n] = oacc1[r];
            }
        }
        __syncthreads();
        if (team == 0) {
            float* ob = out + ((size_t)l * kHQ + h * kG + n) * kD;
            const int d0 = tw * 32 + quad * 4;
            float4 v0, v1;
            #pragma unroll
            for (int r = 0; r < 4; ++r) {
                (&v0.x)[r] = oacc0[r] + Ored[(d0 + r) * 16 + n];
                (&v1.x)[r] = oacc1[r] + Ored[(d0 + 16 + r) * 16 + n];
            }
            *(float4*)(ob + d0)      = v0;
            *(float4*)(ob + d0 + 16) = v1;
        }
    }
}

} // namespace

extern "C" void kernel_launch(void* const* d_in, const int* in_sizes, int n_in,
                              void* d_out, int out_size, void* d_ws, size_t ws_size,
                              hipStream_t stream)
{
    const float* q    = (const float*)d_in[0];
    const float* k    = (const float*)d_in[1];
    const float* v    = (const float*)d_in[2];
    const float* w    = (const float*)d_in[3];
    const int*   bidx = (const int*)d_in[4];
    float* out = (float*)d_out;

    uint4* kp = (uint4*)d_ws;                                   // 2 MB
    uint4* vp = (uint4*)((char*)d_ws + (size_t)kKPackN * 16);   // 2 MB

    pack_kv<<<dim3(512), dim3(256), 0, stream>>>(k, v, kp, vp);
    hsa_main<<<dim3(kLq * kH), dim3(512), 0, stream>>>(q, w, bidx, kp, vp, out);
}

// Round 13
// 91.033 us; speedup vs baseline: 1.2664x; 1.0307x over previous
//
#include <hip/hip_runtime.h>
#include <hip/hip_bf16.h>

// HSA prefill R13 = R12 with V fragments in REGISTERS (vbuf/DMA removed).
// R12 insight: V frags are written and read by the SAME wave -> the LDS
// round-trip (4 b128 reads + DMA + drain exposure per iter) was pure
// overhead. V now lives in 4 uint4 regs with prefetch-distance-1: issued
// right after PV(jp) consumes the old ones, in flight through scores(jp+1)
// (~500 cyc), ~complete at barrier(jp+1)'s vmcnt(0) drain, consumed at
// PV(jp+1). K regs keep R12's post-barrier prefetch. LDS now holds only the
// genuinely cross-wave data (unnormalized P + psum partials, ~10 KB) plus an
// 8 KB epilogue combine buffer. Two teams x 8 waves, 8 barriers total,
// no atomics, no memset.

namespace {

constexpr int kLq = 256, kHQ = 32, kH = 2, kG = 16, kD = 128, kS = 16;
constexpr int kNB = 64;                    // Lkv/BS: distinct blocks per head
constexpr float kScaleLog2e = 0.08838834764831845f * 1.4426950408889634f;

constexpr int kKPackN = kH * kNB * 16 * 64;  // uint4 elems per array (2 MB)
constexpr int kPStr   = 72;                  // P row stride (shorts), 16B-mult
constexpr int kSStr   = 136;                 // pack LDS row stride (shorts)

typedef short s16x8 __attribute__((ext_vector_type(8)));
typedef float f32x4 __attribute__((ext_vector_type(4)));

union U32BF2 { unsigned int u; __hip_bfloat162 h; };
union FragU  { uint4 u; s16x8 v; };

static __device__ inline unsigned int pk_bf16(float a, float b) {
    U32BF2 z; z.h = __float22bfloat162_rn(make_float2(a, b));
    return z.u;
}

// ---------------- pack kernel: 512 wgs, each handles half a block ----------
// K_packed idx = ((h*64+blk)*16 + t*4+st)*64 + lane (lane = quad*16+n)
//   holds K[u = blk*64 + t*16 + n][h][d = st*32 + quad*8 + j]
// V_packed idx = ((h*64+blk)*16 + dt*2+st)*64 + lane
//   holds V[u = blk*64 + st*32 + quad*8 + j][h][d = dt*16 + n]
__global__ __launch_bounds__(256)
void pack_kv(const float* __restrict__ k, const float* __restrict__ v,
             uint4* __restrict__ kp, uint4* __restrict__ vp)
{
    __shared__ unsigned short S_s[32 * kSStr];   // 8.7 KB bf16 [u_loc][d]

    const int bid  = blockIdx.x;                 // 0..511
    const int isV  = bid & 1;
    const int half = (bid >> 1) & 1;
    const int blk  = (bid >> 2) & 63;
    const int h    = bid >> 8;
    const int t    = threadIdx.x;
    const int lane = t & 63, n = lane & 15, quad = lane >> 4;
    const int wv   = t >> 6;                     // 0..3

    {   // coalesced load 32 rows x 128 fp32 -> bf16 LDS
        const float* src = (isV ? v : k) +
            ((size_t)(blk * 64 + half * 32) * kH + h) * kD;
        const int r0 = t >> 5, c4 = (t & 31) << 2;
        #pragma unroll
        for (int p = 0; p < 4; ++p) {
            const int r = p * 8 + r0;
            const float4 f = *(const float4*)(src + (size_t)r * (kH * kD) + c4);
            *(unsigned int*)&S_s[r * kSStr + c4]     = pk_bf16(f.x, f.y);
            *(unsigned int*)&S_s[r * kSStr + c4 + 2] = pk_bf16(f.z, f.w);
        }
    }
    __syncthreads();

    const size_t obase = (size_t)(h * 64 + blk) * 16 * 64;
    if (!isV) {
        #pragma unroll
        for (int rep = 0; rep < 2; ++rep) {
            const int cl    = wv * 2 + rep;      // 0..7
            const int t_loc = cl >> 2, st = cl & 3;
            const int c     = (2 * half + t_loc) * 4 + st;
            const int u_loc = t_loc * 16 + n;
            kp[obase + (size_t)c * 64 + lane] =
                *(const uint4*)&S_s[u_loc * kSStr + st * 32 + quad * 8];
        }
    } else {
        #pragma unroll
        for (int rep = 0; rep < 2; ++rep) {
            const int dt = wv * 2 + rep;         // 0..7
            const int c  = dt * 2 + half;
            const int d  = dt * 16 + n;
            unsigned short s[8];
            #pragma unroll
            for (int j = 0; j < 8; ++j) s[j] = S_s[(quad * 8 + j) * kSStr + d];
            uint4 val;
            val.x = s[0] | ((unsigned)s[1] << 16);
            val.y = s[2] | ((unsigned)s[3] << 16);
            val.z = s[4] | ((unsigned)s[5] << 16);
            val.w = s[6] | ((unsigned)s[7] << 16);
            vp[obase + (size_t)c * 64 + lane] = val;
        }
    }
}

// ---------------- main kernel --------------------------------------------
__global__ __launch_bounds__(512, 4)
void hsa_main(const float* __restrict__ q, const float* __restrict__ w,
              const int* __restrict__ bidx, const uint4* __restrict__ kp,
              const uint4* __restrict__ vp, float* __restrict__ out)
{
    __shared__ __align__(16) unsigned short P_s[2][2][kG * kPStr];   // 9.2 KB
    __shared__ __align__(16) float psum[2][2][kG][4];                // 1 KB
    __shared__ __align__(16) float Ored[kD * kG];                    // 8 KB epilogue

    const int bid  = blockIdx.x;                 // 0..511
    const int l    = bid >> 1;
    const int h    = bid & 1;
    const int tid  = threadIdx.x;
    const int wave = tid >> 6;
    const int team = wave >> 2;                  // 0,1
    const int tw   = wave & 3;                   // wave-in-team
    const int lane = tid & 63;
    const int n    = lane & 15;
    const int quad = lane >> 4;

    // Q B-frags: lane g=n, k = st*32 + quad*8 + j
    s16x8 qf[4];
    {
        const float* qb = q + ((size_t)l * kHQ + h * kG + n) * kD + quad * 8;
        #pragma unroll
        for (int st = 0; st < 4; ++st) {
            const float4 f0 = *(const float4*)(qb + st * 32);
            const float4 f1 = *(const float4*)(qb + st * 32 + 4);
            union { s16x8 v; unsigned int u[4]; } z;
            z.u[0] = pk_bf16(f0.x, f0.y); z.u[1] = pk_bf16(f0.z, f0.w);
            z.u[2] = pk_bf16(f1.x, f1.y); z.u[3] = pk_bf16(f1.z, f1.w);
            qf[st] = z.v;
        }
    }

    // this team's 8 s-slots (s = 2*jp + team): bases (wave-uniform) + weights
    int   base8[8];
    float wval8[8];
    #pragma unroll
    for (int j = 0; j < 8; ++j) {
        const int s  = 2 * j + team;
        const int bi = bidx[(size_t)(l * kH + h) * kS + s];
        wval8[j] = (bi < 0) ? 0.f : w[((size_t)l * kHQ + h * kG + n) * kS + s];
        base8[j] = (h * kNB + max(bi, 0)) * 1024;   // uint4 idx
    }

    // prologue: K(pair 0) then V(pair 0) frags in flight. Scores wait only on
    // the first 4 (kreg); vreg stays outstanding until PV(0).
    FragU kreg[4], vreg[4];
    #pragma unroll
    for (int st = 0; st < 4; ++st)
        kreg[st].u = kp[base8[0] + (tw * 4 + st) * 64 + lane];
    #pragma unroll
    for (int i = 0; i < 4; ++i)
        vreg[i].u = vp[base8[0] + (tw * 4 + i) * 64 + lane];
    __builtin_amdgcn_sched_barrier(0);

    f32x4 oacc0 = {0.f, 0.f, 0.f, 0.f};   // d-tile 2*tw   (team partial)
    f32x4 oacc1 = {0.f, 0.f, 0.f, 0.f};   // d-tile 2*tw+1 (team partial)

    #pragma unroll
    for (int jp = 0; jp < 8; ++jp) {
        const int cur = jp & 1;

        // ---- scores: wave owns u-tile tw of its team's block ----
        f32x4 sc = {0.f, 0.f, 0.f, 0.f};
        #pragma unroll
        for (int st = 0; st < 4; ++st)
            sc = __builtin_amdgcn_mfma_f32_16x16x32_bf16(kreg[st].v, qf[st], sc, 0, 0, 0);

        // ---- exp (4/lane) + wave-partial denominator ----
        float part = 0.f;
        #pragma unroll
        for (int r = 0; r < 4; ++r) {
            sc[r] = exp2f(sc[r] * kScaleLog2e);
            part += sc[r];
        }
        part += __shfl_xor(part, 16);
        part += __shfl_xor(part, 32);
        if (quad == 0) psum[cur][team][n][tw] = part;

        // ---- UNNORMALIZED P -> team LDS slot (B-frag order) ----
        const unsigned long long pq =
            ((unsigned long long)pk_bf16(sc[2], sc[3]) << 32) | pk_bf16(sc[0], sc[1]);
        *(unsigned long long*)&P_s[cur][team][n * kPStr + tw * 16 + quad * 4] = pq;

        // barrier: psum/P visible. vmcnt(0) drain covers only vreg[jp]
        // (issued at end of iter jp-1, ~a full scores+exp phase ago).
        __syncthreads();

        // ---- post-barrier: K[jp+1] prefetch (consumed at scores jp+1) ----
        if (jp < 7) {
            #pragma unroll
            for (int st = 0; st < 4; ++st)
                kreg[st].u = kp[base8[jp + 1] + (tw * 4 + st) * 64 + lane];
        }
        __builtin_amdgcn_sched_barrier(0);

        // ---- denominator + per-lane coef (lane n owns output column g=n) ----
        const float4 ps  = *(const float4*)&psum[cur][team][n][0];
        const float coef = wval8[jp] / (ps.x + ps.y + ps.z + ps.w);
        const s16x8 bf0 = *(const s16x8*)&P_s[cur][team][n * kPStr + quad * 8];
        const s16x8 bf1 = *(const s16x8*)&P_s[cur][team][n * kPStr + 32 + quad * 8];

        // ---- PV into fresh pacc, then oacc += coef * pacc ----
        const f32x4 zero = {0.f, 0.f, 0.f, 0.f};
        f32x4 p0 = __builtin_amdgcn_mfma_f32_16x16x32_bf16(vreg[0].v, bf0, zero, 0, 0, 0);
        p0       = __builtin_amdgcn_mfma_f32_16x16x32_bf16(vreg[1].v, bf1, p0,   0, 0, 0);
        f32x4 p1 = __builtin_amdgcn_mfma_f32_16x16x32_bf16(vreg[2].v, bf0, zero, 0, 0, 0);
        p1       = __builtin_amdgcn_mfma_f32_16x16x32_bf16(vreg[3].v, bf1, p1,   0, 0, 0);
        #pragma unroll
        for (int r = 0; r < 4; ++r) {
            oacc0[r] = fmaf(coef, p0[r], oacc0[r]);
            oacc1[r] = fmaf(coef, p1[r], oacc1[r]);
        }

        // ---- V[jp+1] prefetch: issued NOW (vreg dead), in flight through
        //      scores(jp+1), ~complete at barrier(jp+1), used at PV(jp+1) ----
        if (jp < 7) {
            #pragma unroll
            for (int i = 0; i < 4; ++i)
                vreg[i].u = vp[base8[jp + 1] + (tw * 4 + i) * 64 + lane];
        }
        __builtin_amdgcn_sched_barrier(0);
    }

    // ---- combine the two teams' partials via LDS, store ----
    __syncthreads();
    if (team == 1) {
        #pragma unroll
        for (int r = 0; r < 4; ++r) {
            Ored[((tw * 2 + 0) * 16 + quad * 4 + r) * 16 + n] = oacc0[r];
            Ored[((tw * 2 + 1) * 16 + quad * 4 + r) * 16 + n] = oacc1[r];
        }
    }
    __syncthreads();
    if (team == 0) {
        float* ob = out + ((size_t)l * kHQ + h * kG + n) * kD;
        const int d0 = tw * 32 + quad * 4;
        float4 v0, v1;
        #pragma unroll
        for (int r = 0; r < 4; ++r) {
            (&v0.x)[r] = oacc0[r] + Ored[(d0 + r) * 16 + n];
            (&v1.x)[r] = oacc1[r] + Ored[(d0 + 16 + r) * 16 + n];
        }
        *(float4*)(ob + d0)      = v0;
        *(float4*)(ob + d0 + 16) = v1;
    }
}

} // namespace

extern "C" void kernel_launch(void* const* d_in, const int* in_sizes, int n_in,
                              void* d_out, int out_size, void* d_ws, size_t ws_size,
                              hipStream_t stream)
{
    const float* q    = (const float*)d_in[0];
    const float* k    = (const float*)d_in[1];
    const float* v    = (const float*)d_in[2];
    const float* w    = (const float*)d_in[3];
    const int*   bidx = (const int*)d_in[4];
    float* out = (float*)d_out;

    uint4* kp = (uint4*)d_ws;                                   // 2 MB
    uint4* vp = (uint4*)((char*)d_ws + (size_t)kKPackN * 16);   // 2 MB

    pack_kv<<<dim3(512), dim3(256), 0, stream>>>(k, v, kp, vp);
    hsa_main<<<dim3(kLq * kH), dim3(512), 0, stream>>>(q, w, bidx, kp, vp, out);
}

// Round 14
// 89.015 us; speedup vs baseline: 1.2951x; 1.0227x over previous
//
#include <hip/hip_runtime.h>
#include <hip/hip_bf16.h>

// HSA prefill R14: barrier-free wave-owns-block main loop.
// R13 residual (~17 us over the ~8 us L2 floor) attributed to lockstep: 8
// wg-wide barriers x 16 waves convert per-wave jitter + prefetch exposure
// into whole-CU bubbles. R14 removes ALL loop barriers: each wave owns 2
// s-blocks end-to-end (full 64ux16g score tile = 16 MFMA -> fully intra-wave
// softmax -> P via PRIVATE LDS slice (same-wave RAW, lgkmcnt only) -> PV all
// 8 d-tiles = 16 MFMA). 512-thr wgs keep 16 waves/CU (4/SIMD) for organic
// m114-style co-scheduling. Loads stream through banked register groups with
// sched_barrier(0)-pinned issue points (R7 fence lesson); sc reduced to one
// f32x4 (exp-as-you-go) to hold VGPR ~122 <= 128 (2 wgs/CU co-residency).
// Epilogue: 3-round LDS tree-combine (b128, lane*16B = 2-way-free) + direct
// stores. No atomics, no memset.

namespace {

constexpr int kLq = 256, kHQ = 32, kH = 2, kG = 16, kD = 128, kS = 16;
constexpr int kNB = 64;                    // Lkv/BS: distinct blocks per head
constexpr float kScaleLog2e = 0.08838834764831845f * 1.4426950408889634f;

constexpr int kKPackN = kH * kNB * 16 * 64;  // uint4 elems per array (2 MB)
constexpr int kPStr   = 72;                  // P row stride (shorts)
constexpr int kSStr   = 136;                 // pack LDS row stride (shorts)

typedef short s16x8 __attribute__((ext_vector_type(8)));
typedef float f32x4 __attribute__((ext_vector_type(4)));

union U32BF2 { unsigned int u; __hip_bfloat162 h; };
union FragU  { uint4 u; s16x8 v; };

static __device__ inline unsigned int pk_bf16(float a, float b) {
    U32BF2 z; z.h = __float22bfloat162_rn(make_float2(a, b));
    return z.u;
}

// ---------------- pack kernel (unchanged, 512 wgs, ~5 us) ------------------
// K_packed idx = ((h*64+blk)*16 + t*4+st)*64 + lane (lane = quad*16+n)
//   holds K[u = blk*64 + t*16 + n][h][d = st*32 + quad*8 + j]
// V_packed idx = ((h*64+blk)*16 + dt*2+st)*64 + lane
//   holds V[u = blk*64 + st*32 + quad*8 + j][h][d = dt*16 + n]
__global__ __launch_bounds__(256)
void pack_kv(const float* __restrict__ k, const float* __restrict__ v,
             uint4* __restrict__ kp, uint4* __restrict__ vp)
{
    __shared__ unsigned short S_s[32 * kSStr];   // 8.7 KB bf16 [u_loc][d]

    const int bid  = blockIdx.x;                 // 0..511
    const int isV  = bid & 1;
    const int half = (bid >> 1) & 1;
    const int blk  = (bid >> 2) & 63;
    const int h    = bid >> 8;
    const int t    = threadIdx.x;
    const int lane = t & 63, n = lane & 15, quad = lane >> 4;
    const int wv   = t >> 6;                     // 0..3

    {   // coalesced load 32 rows x 128 fp32 -> bf16 LDS
        const float* src = (isV ? v : k) +
            ((size_t)(blk * 64 + half * 32) * kH + h) * kD;
        const int r0 = t >> 5, c4 = (t & 31) << 2;
        #pragma unroll
        for (int p = 0; p < 4; ++p) {
            const int r = p * 8 + r0;
            const float4 f = *(const float4*)(src + (size_t)r * (kH * kD) + c4);
            *(unsigned int*)&S_s[r * kSStr + c4]     = pk_bf16(f.x, f.y);
            *(unsigned int*)&S_s[r * kSStr + c4 + 2] = pk_bf16(f.z, f.w);
        }
    }
    __syncthreads();

    const size_t obase = (size_t)(h * 64 + blk) * 16 * 64;
    if (!isV) {
        #pragma unroll
        for (int rep = 0; rep < 2; ++rep) {
            const int cl    = wv * 2 + rep;      // 0..7
            const int t_loc = cl >> 2, st = cl & 3;
            const int c     = (2 * half + t_loc) * 4 + st;
            const int u_loc = t_loc * 16 + n;
            kp[obase + (size_t)c * 64 + lane] =
                *(const uint4*)&S_s[u_loc * kSStr + st * 32 + quad * 8];
        }
    } else {
        #pragma unroll
        for (int rep = 0; rep < 2; ++rep) {
            const int dt = wv * 2 + rep;         // 0..7
            const int c  = dt * 2 + half;
            const int d  = dt * 16 + n;
            unsigned short s[8];
            #pragma unroll
            for (int j = 0; j < 8; ++j) s[j] = S_s[(quad * 8 + j) * kSStr + d];
            uint4 val;
            val.x = s[0] | ((unsigned)s[1] << 16);
            val.y = s[2] | ((unsigned)s[3] << 16);
            val.z = s[4] | ((unsigned)s[5] << 16);
            val.w = s[6] | ((unsigned)s[7] << 16);
            vp[obase + (size_t)c * 64 + lane] = val;
        }
    }
}

// ---------------- main kernel --------------------------------------------
__global__ __launch_bounds__(512, 4)
void hsa_main(const float* __restrict__ q, const float* __restrict__ w,
              const int* __restrict__ bidx, const uint4* __restrict__ kp,
              const uint4* __restrict__ vp, float* __restrict__ out)
{
    // union: loop phase = 8 private P slices (8*1152 shorts = 18.4 KB);
    //        epilogue   = 4 combine slots of 2048 floats (32 KB)
    __shared__ __align__(16) float smem[8192];                   // 32 KB

    const int bid  = blockIdx.x;                 // 0..511
    const int l    = bid >> 1;
    const int h    = bid & 1;
    const int tid  = threadIdx.x;
    const int wave = tid >> 6;                   // 0..7
    const int lane = tid & 63;
    const int n    = lane & 15;
    const int quad = lane >> 4;

    // Q B-frags: lane g=n, k = st*32 + quad*8 + j
    s16x8 qf[4];
    {
        const float* qb = q + ((size_t)l * kHQ + h * kG + n) * kD + quad * 8;
        #pragma unroll
        for (int st = 0; st < 4; ++st) {
            const float4 f0 = *(const float4*)(qb + st * 32);
            const float4 f1 = *(const float4*)(qb + st * 32 + 4);
            union { s16x8 v; unsigned int u[4]; } z;
            z.u[0] = pk_bf16(f0.x, f0.y); z.u[1] = pk_bf16(f0.z, f0.w);
            z.u[2] = pk_bf16(f1.x, f1.y); z.u[3] = pk_bf16(f1.z, f1.w);
            qf[st] = z.v;
        }
    }

    // this wave's 2 s-blocks: s = wave*2 + jb
    int   base2[2];
    float wval2[2];
    #pragma unroll
    for (int j = 0; j < 2; ++j) {
        const int s  = wave * 2 + j;
        const int bi = bidx[(size_t)(l * kH + h) * kS + s];
        wval2[j] = (bi < 0) ? 0.f : w[((size_t)l * kHQ + h * kG + n) * kS + s];
        base2[j] = (h * kNB + max(bi, 0)) * 1024;   // uint4 idx
    }

    unsigned short* Pw = (unsigned short*)smem + wave * (kG * kPStr);

    // streamed register banks
    FragU kA[4], kB[4], vr[4];
    #pragma unroll
    for (int st = 0; st < 4; ++st) kA[st].u = kp[base2[0] + (0 * 4 + st) * 64 + lane];
    #pragma unroll
    for (int st = 0; st < 4; ++st) kB[st].u = kp[base2[0] + (1 * 4 + st) * 64 + lane];
    #pragma unroll
    for (int i = 0; i < 4; ++i)    vr[i].u  = vp[base2[0] + i * 64 + lane];
    __builtin_amdgcn_sched_barrier(0);

    f32x4 oacc[8];
    #pragma unroll
    for (int dt = 0; dt < 8; ++dt) oacc[dt] = (f32x4){0.f, 0.f, 0.f, 0.f};

    #pragma unroll
    for (int jb = 0; jb < 2; ++jb) {
        // ---- scores: 4 u-tiles, exp-as-you-go, P -> private LDS slice ----
        float part = 0.f;
        #pragma unroll
        for (int t = 0; t < 4; ++t) {
            FragU* cur = (t & 1) ? kB : kA;
            f32x4 sc = {0.f, 0.f, 0.f, 0.f};
            #pragma unroll
            for (int st = 0; st < 4; ++st)
                sc = __builtin_amdgcn_mfma_f32_16x16x32_bf16(cur[st].v, qf[st], sc, 0, 0, 0);

            // refill the consumed bank: t<2 -> this block's group t+2;
            // t>=2 -> next block's group t-2 (only when jb==0)
            if (t < 2) {
                #pragma unroll
                for (int st = 0; st < 4; ++st)
                    cur[st].u = kp[base2[jb] + ((t + 2) * 4 + st) * 64 + lane];
            } else if (jb == 0) {
                #pragma unroll
                for (int st = 0; st < 4; ++st)
                    cur[st].u = kp[base2[1] + ((t - 2) * 4 + st) * 64 + lane];
            }
            __builtin_amdgcn_sched_barrier(0);

            #pragma unroll
            for (int r = 0; r < 4; ++r) {
                sc[r] = exp2f(sc[r] * kScaleLog2e);
                part += sc[r];
            }
            const unsigned long long pq =
                ((unsigned long long)pk_bf16(sc[2], sc[3]) << 32) | pk_bf16(sc[0], sc[1]);
            *(unsigned long long*)&Pw[n * kPStr + t * 16 + quad * 4] = pq;
        }

        // ---- fully intra-wave denominator + coef ----
        part += __shfl_xor(part, 16);
        part += __shfl_xor(part, 32);
        const float coef = wval2[jb] / part;

        // ---- P B-frags from private slice (same-wave RAW, lgkmcnt) ----
        const s16x8 bf0 = *(const s16x8*)&Pw[n * kPStr + quad * 8];
        const s16x8 bf1 = *(const s16x8*)&Pw[n * kPStr + 32 + quad * 8];

        // ---- PV: 4 V-groups of 2 d-tiles, group-streamed ----
        const f32x4 zero = {0.f, 0.f, 0.f, 0.f};
        #pragma unroll
        for (int vg = 0; vg < 4; ++vg) {
            const int dt0 = vg * 2;
            f32x4 p0 = __builtin_amdgcn_mfma_f32_16x16x32_bf16(vr[0].v, bf0, zero, 0, 0, 0);
            p0       = __builtin_amdgcn_mfma_f32_16x16x32_bf16(vr[1].v, bf1, p0,   0, 0, 0);
            f32x4 p1 = __builtin_amdgcn_mfma_f32_16x16x32_bf16(vr[2].v, bf0, zero, 0, 0, 0);
            p1       = __builtin_amdgcn_mfma_f32_16x16x32_bf16(vr[3].v, bf1, p1,   0, 0, 0);

            // refill vr: next group of this block, or next block's group 0
            if (vg < 3) {
                #pragma unroll
                for (int i = 0; i < 4; ++i)
                    vr[i].u = vp[base2[jb] + ((vg + 1) * 4 + i) * 64 + lane];
            } else if (jb == 0) {
                #pragma unroll
                for (int i = 0; i < 4; ++i)
                    vr[i].u = vp[base2[1] + i * 64 + lane];
            }
            __builtin_amdgcn_sched_barrier(0);

            #pragma unroll
            for (int r = 0; r < 4; ++r) {
                oacc[dt0 + 0][r] = fmaf(coef, p0[r], oacc[dt0 + 0][r]);
                oacc[dt0 + 1][r] = fmaf(coef, p1[r], oacc[dt0 + 1][r]);
            }
        }
    }

    // ---- epilogue: 3-round LDS tree-combine of 8 waves' O-partials ----
    // slot layout: epi[slot*2048 + dt*256 + lane*4 + r] (lane*16B: 2-way-free)
    __syncthreads();                       // P slices dead; smem -> epi
    float* epi = smem;

    if (wave >= 4) {                       // round 1: waves 4..7 -> slots 0..3
        #pragma unroll
        for (int dt = 0; dt < 8; ++dt)
            *(f32x4*)&epi[(wave - 4) * 2048 + dt * 256 + lane * 4] = oacc[dt];
    }
    __syncthreads();
    if (wave < 4) {
        #pragma unroll
        for (int dt = 0; dt < 8; ++dt) {
            const f32x4 o = *(const f32x4*)&epi[wave * 2048 + dt * 256 + lane * 4];
            #pragma unroll
            for (int r = 0; r < 4; ++r) oacc[dt][r] += o[r];
        }
    }
    __syncthreads();
    if (wave == 2 || wave == 3) {          // round 2: waves 2,3 -> slots 0,1
        #pragma unroll
        for (int dt = 0; dt < 8; ++dt)
            *(f32x4*)&epi[(wave - 2) * 2048 + dt * 256 + lane * 4] = oacc[dt];
    }
    __syncthreads();
    if (wave < 2) {
        #pragma unroll
        for (int dt = 0; dt < 8; ++dt) {
            const f32x4 o = *(const f32x4*)&epi[wave * 2048 + dt * 256 + lane * 4];
            #pragma unroll
            for (int r = 0; r < 4; ++r) oacc[dt][r] += o[r];
        }
    }
    __syncthreads();
    if (wave == 1) {                       // round 3: wave 1 -> slot 0
        #pragma unroll
        for (int dt = 0; dt < 8; ++dt)
            *(f32x4*)&epi[dt * 256 + lane * 4] = oacc[dt];
    }
    __syncthreads();
    if (wave == 0) {
        float* ob = out + ((size_t)l * kHQ + h * kG + n) * kD;
        #pragma unroll
        for (int dt = 0; dt < 8; ++dt) {
            const f32x4 o = *(const f32x4*)&epi[dt * 256 + lane * 4];
            float4 val;
            #pragma unroll
            for (int r = 0; r < 4; ++r) (&val.x)[r] = oacc[dt][r] + o[r];
            *(float4*)(ob + dt * 16 + quad * 4) = val;
        }
    }
}

} // namespace

extern "C" void kernel_launch(void* const* d_in, const int* in_sizes, int n_in,
                              void* d_out, int out_size, void* d_ws, size_t ws_size,
                              hipStream_t stream)
{
    const float* q    = (const float*)d_in[0];
    const float* k    = (const float*)d_in[1];
    const float* v    = (const float*)d_in[2];
    const float* w    = (const float*)d_in[3];
    const int*   bidx = (const int*)d_in[4];
    float* out = (float*)d_out;

    uint4* kp = (uint4*)d_ws;                                   // 2 MB
    uint4* vp = (uint4*)((char*)d_ws + (size_t)kKPackN * 16);   // 2 MB

    pack_kv<<<dim3(512), dim3(256), 0, stream>>>(k, v, kp, vp);
    hsa_main<<<dim3(kLq * kH), dim3(512), 0, stream>>>(q, w, bidx, kp, vp, out);
}

// Round 15
// 88.810 us; speedup vs baseline: 1.2981x; 1.0023x over previous
//
#include <hip/hip_runtime.h>
#include <hip/hip_bf16.h>

// HSA prefill R15 = R14 + block-pair INTERLEAVED scores (MLP x2, reg-neutral).
// R14 audit: 256MB at 11 TB/s (1/3 of L2 BW) with ~1 load in flight per wave
// -> K refill distance (1 group ~200cyc) and the 4-MFMA serial accumulator
// chain dominate. R15: each wave owns blocks A,B; scores interleave
// A-t / B-t so each bank refill has a full other-block group (~300-400 cyc)
// before consumption and the MFMA chains of A hide under B's work.
// Register budget held <=128 by moving Q fragments to a per-wave LDS slice
// (-16 VGPR, 4 ds_read_b128 per group, covered by interleave). P gets two
// per-wave slices (A,B); PV phases stay sequential and identical to R14
// (vr group-streaming, oacc += coef*pacc). Epilogue = R14 tree-combine,
// reusing the qf LDS region. LDS ~69 KB/wg (2 wg/CU), no atomics, no memset.

namespace {

constexpr int kLq = 256, kHQ = 32, kH = 2, kG = 16, kD = 128, kS = 16;
constexpr int kNB = 64;                    // Lkv/BS: distinct blocks per head
constexpr float kScaleLog2e = 0.08838834764831845f * 1.4426950408889634f;

constexpr int kKPackN = kH * kNB * 16 * 64;  // uint4 elems per array (2 MB)
constexpr int kPStr   = 72;                  // P row stride (shorts)
constexpr int kSStr   = 136;                 // pack LDS row stride (shorts)

// main-kernel LDS layout (bytes):
//   [0, 32768)        qf slices:  wave*4096 + st*1024 + lane*16   (epilogue reuse)
//   [32768, 69632)    P slices:   wave*4608 + blk*2304 + (n*72+u)*2
constexpr int kQOff = 0;
constexpr int kPOff = 32768;

typedef short s16x8 __attribute__((ext_vector_type(8)));
typedef float f32x4 __attribute__((ext_vector_type(4)));

union U32BF2 { unsigned int u; __hip_bfloat162 h; };
union FragU  { uint4 u; s16x8 v; };

static __device__ inline unsigned int pk_bf16(float a, float b) {
    U32BF2 z; z.h = __float22bfloat162_rn(make_float2(a, b));
    return z.u;
}

// ---------------- pack kernel (unchanged, 512 wgs, ~5 us) ------------------
// K_packed idx = ((h*64+blk)*16 + t*4+st)*64 + lane (lane = quad*16+n)
//   holds K[u = blk*64 + t*16 + n][h][d = st*32 + quad*8 + j]
// V_packed idx = ((h*64+blk)*16 + dt*2+st)*64 + lane
//   holds V[u = blk*64 + st*32 + quad*8 + j][h][d = dt*16 + n]
__global__ __launch_bounds__(256)
void pack_kv(const float* __restrict__ k, const float* __restrict__ v,
             uint4* __restrict__ kp, uint4* __restrict__ vp)
{
    __shared__ unsigned short S_s[32 * kSStr];   // 8.7 KB bf16 [u_loc][d]

    const int bid  = blockIdx.x;                 // 0..511
    const int isV  = bid & 1;
    const int half = (bid >> 1) & 1;
    const int blk  = (bid >> 2) & 63;
    const int h    = bid >> 8;
    const int t    = threadIdx.x;
    const int lane = t & 63, n = lane & 15, quad = lane >> 4;
    const int wv   = t >> 6;                     // 0..3

    {   // coalesced load 32 rows x 128 fp32 -> bf16 LDS
        const float* src = (isV ? v : k) +
            ((size_t)(blk * 64 + half * 32) * kH + h) * kD;
        const int r0 = t >> 5, c4 = (t & 31) << 2;
        #pragma unroll
        for (int p = 0; p < 4; ++p) {
            const int r = p * 8 + r0;
            const float4 f = *(const float4*)(src + (size_t)r * (kH * kD) + c4);
            *(unsigned int*)&S_s[r * kSStr + c4]     = pk_bf16(f.x, f.y);
            *(unsigned int*)&S_s[r * kSStr + c4 + 2] = pk_bf16(f.z, f.w);
        }
    }
    __syncthreads();

    const size_t obase = (size_t)(h * 64 + blk) * 16 * 64;
    if (!isV) {
        #pragma unroll
        for (int rep = 0; rep < 2; ++rep) {
            const int cl    = wv * 2 + rep;      // 0..7
            const int t_loc = cl >> 2, st = cl & 3;
            const int c     = (2 * half + t_loc) * 4 + st;
            const int u_loc = t_loc * 16 + n;
            kp[obase + (size_t)c * 64 + lane] =
                *(const uint4*)&S_s[u_loc * kSStr + st * 32 + quad * 8];
        }
    } else {
        #pragma unroll
        for (int rep = 0; rep < 2; ++rep) {
            const int dt = wv * 2 + rep;         // 0..7
            const int c  = dt * 2 + half;
            const int d  = dt * 16 + n;
            unsigned short s[8];
            #pragma unroll
            for (int j = 0; j < 8; ++j) s[j] = S_s[(quad * 8 + j) * kSStr + d];
            uint4 val;
            val.x = s[0] | ((unsigned)s[1] << 16);
            val.y = s[2] | ((unsigned)s[3] << 16);
            val.z = s[4] | ((unsigned)s[5] << 16);
            val.w = s[6] | ((unsigned)s[7] << 16);
            vp[obase + (size_t)c * 64 + lane] = val;
        }
    }
}

// ---------------- main kernel --------------------------------------------
__global__ __launch_bounds__(512, 4)
void hsa_main(const float* __restrict__ q, const float* __restrict__ w,
              const int* __restrict__ bidx, const uint4* __restrict__ kp,
              const uint4* __restrict__ vp, float* __restrict__ out)
{
    __shared__ __align__(16) unsigned char smem[69632];   // 68 KB (see layout)

    const int bid  = blockIdx.x;                 // 0..511
    const int l    = bid >> 1;
    const int h    = bid & 1;
    const int tid  = threadIdx.x;
    const int wave = tid >> 6;                   // 0..7
    const int lane = tid & 63;
    const int n    = lane & 15;
    const int quad = lane >> 4;

    // ---- Q B-frags -> per-wave LDS slice (frees 16 VGPR) ----
    unsigned char* qlds = smem + kQOff + wave * 4096 + lane * 16;
    {
        const float* qb = q + ((size_t)l * kHQ + h * kG + n) * kD + quad * 8;
        #pragma unroll
        for (int st = 0; st < 4; ++st) {
            const float4 f0 = *(const float4*)(qb + st * 32);
            const float4 f1 = *(const float4*)(qb + st * 32 + 4);
            uint4 z;
            z.x = pk_bf16(f0.x, f0.y); z.y = pk_bf16(f0.z, f0.w);
            z.z = pk_bf16(f1.x, f1.y); z.w = pk_bf16(f1.z, f1.w);
            *(uint4*)(qlds + st * 1024) = z;
        }
    }

    // this wave's 2 s-blocks A,B: s = wave*2 + {0,1}
    int   baseA, baseB;
    float wvalA, wvalB;
    {
        const int sA = wave * 2, sB = wave * 2 + 1;
        const int biA = bidx[(size_t)(l * kH + h) * kS + sA];
        const int biB = bidx[(size_t)(l * kH + h) * kS + sB];
        wvalA = (biA < 0) ? 0.f : w[((size_t)l * kHQ + h * kG + n) * kS + sA];
        wvalB = (biB < 0) ? 0.f : w[((size_t)l * kHQ + h * kG + n) * kS + sB];
        baseA = (h * kNB + max(biA, 0)) * 1024;
        baseB = (h * kNB + max(biB, 0)) * 1024;
    }

    unsigned short* PA = (unsigned short*)(smem + kPOff + wave * 4608);
    unsigned short* PB = PA + kG * kPStr;

    // prologue: kA <- A group0, kB <- B group0, vr <- A V-group0 (12 in flight)
    FragU kA[4], kB[4], vr[4];
    #pragma unroll
    for (int st = 0; st < 4; ++st) kA[st].u = kp[baseA + st * 64 + lane];
    #pragma unroll
    for (int st = 0; st < 4; ++st) kB[st].u = kp[baseB + st * 64 + lane];
    #pragma unroll
    for (int i = 0; i < 4; ++i)    vr[i].u  = vp[baseA + i * 64 + lane];
    __builtin_amdgcn_sched_barrier(0);

    f32x4 oacc[8];
    #pragma unroll
    for (int dt = 0; dt < 8; ++dt) oacc[dt] = (f32x4){0.f, 0.f, 0.f, 0.f};

    // ---- interleaved scores: A-t, B-t alternate; refills get a full
    //      other-block group (~300-400 cyc) before consumption ----
    float partA = 0.f, partB = 0.f;
    #pragma unroll
    for (int t = 0; t < 4; ++t) {
        {   // A group t
            f32x4 sc = {0.f, 0.f, 0.f, 0.f};
            #pragma unroll
            for (int st = 0; st < 4; ++st) {
                const s16x8 aq = *(const s16x8*)(qlds + st * 1024);
                sc = __builtin_amdgcn_mfma_f32_16x16x32_bf16(kA[st].v, aq, sc, 0, 0, 0);
            }
            if (t < 3) {
                #pragma unroll
                for (int st = 0; st < 4; ++st)
                    kA[st].u = kp[baseA + ((t + 1) * 4 + st) * 64 + lane];
            }
            __builtin_amdgcn_sched_barrier(0);
            #pragma unroll
            for (int r = 0; r < 4; ++r) {
                sc[r] = exp2f(sc[r] * kScaleLog2e);
                partA += sc[r];
            }
            const unsigned long long pq =
                ((unsigned long long)pk_bf16(sc[2], sc[3]) << 32) | pk_bf16(sc[0], sc[1]);
            *(unsigned long long*)&PA[n * kPStr + t * 16 + quad * 4] = pq;
        }
        {   // B group t
            f32x4 sc = {0.f, 0.f, 0.f, 0.f};
            #pragma unroll
            for (int st = 0; st < 4; ++st) {
                const s16x8 aq = *(const s16x8*)(qlds + st * 1024);
                sc = __builtin_amdgcn_mfma_f32_16x16x32_bf16(kB[st].v, aq, sc, 0, 0, 0);
            }
            if (t < 3) {
                #pragma unroll
                for (int st = 0; st < 4; ++st)
                    kB[st].u = kp[baseB + ((t + 1) * 4 + st) * 64 + lane];
            }
            __builtin_amdgcn_sched_barrier(0);
            #pragma unroll
            for (int r = 0; r < 4; ++r) {
                sc[r] = exp2f(sc[r] * kScaleLog2e);
                partB += sc[r];
            }
            const unsigned long long pq =
                ((unsigned long long)pk_bf16(sc[2], sc[3]) << 32) | pk_bf16(sc[0], sc[1]);
            *(unsigned long long*)&PB[n * kPStr + t * 16 + quad * 4] = pq;
        }
    }

    // ---- intra-wave denominators ----
    partA += __shfl_xor(partA, 16);
    partA += __shfl_xor(partA, 32);
    partB += __shfl_xor(partB, 16);
    partB += __shfl_xor(partB, 32);
    const float coefA = wvalA / partA;
    const float coefB = wvalB / partB;

    // ---- PV(A) then PV(B), R14-style group streaming ----
    const f32x4 zero = {0.f, 0.f, 0.f, 0.f};
    {
        const s16x8 bf0 = *(const s16x8*)&PA[n * kPStr + quad * 8];
        const s16x8 bf1 = *(const s16x8*)&PA[n * kPStr + 32 + quad * 8];
        #pragma unroll
        for (int vg = 0; vg < 4; ++vg) {
            const int dt0 = vg * 2;
            f32x4 p0 = __builtin_amdgcn_mfma_f32_16x16x32_bf16(vr[0].v, bf0, zero, 0, 0, 0);
            p0       = __builtin_amdgcn_mfma_f32_16x16x32_bf16(vr[1].v, bf1, p0,   0, 0, 0);
            f32x4 p1 = __builtin_amdgcn_mfma_f32_16x16x32_bf16(vr[2].v, bf0, zero, 0, 0, 0);
            p1       = __builtin_amdgcn_mfma_f32_16x16x32_bf16(vr[3].v, bf1, p1,   0, 0, 0);
            if (vg < 3) {
                #pragma unroll
                for (int i = 0; i < 4; ++i)
                    vr[i].u = vp[baseA + ((vg + 1) * 4 + i) * 64 + lane];
            } else {
                #pragma unroll
                for (int i = 0; i < 4; ++i)
                    vr[i].u = vp[baseB + i * 64 + lane];
            }
            __builtin_amdgcn_sched_barrier(0);
            #pragma unroll
            for (int r = 0; r < 4; ++r) {
                oacc[dt0 + 0][r] = fmaf(coefA, p0[r], oacc[dt0 + 0][r]);
                oacc[dt0 + 1][r] = fmaf(coefA, p1[r], oacc[dt0 + 1][r]);
            }
        }
    }
    {
        const s16x8 bf0 = *(const s16x8*)&PB[n * kPStr + quad * 8];
        const s16x8 bf1 = *(const s16x8*)&PB[n * kPStr + 32 + quad * 8];
        #pragma unroll
        for (int vg = 0; vg < 4; ++vg) {
            const int dt0 = vg * 2;
            f32x4 p0 = __builtin_amdgcn_mfma_f32_16x16x32_bf16(vr[0].v, bf0, zero, 0, 0, 0);
            p0       = __builtin_amdgcn_mfma_f32_16x16x32_bf16(vr[1].v, bf1, p0,   0, 0, 0);
            f32x4 p1 = __builtin_amdgcn_mfma_f32_16x16x32_bf16(vr[2].v, bf0, zero, 0, 0, 0);
            p1       = __builtin_amdgcn_mfma_f32_16x16x32_bf16(vr[3].v, bf1, p1,   0, 0, 0);
            if (vg < 3) {
                #pragma unroll
                for (int i = 0; i < 4; ++i)
                    vr[i].u = vp[baseB + ((vg + 1) * 4 + i) * 64 + lane];
            }
            __builtin_amdgcn_sched_barrier(0);
            #pragma unroll
            for (int r = 0; r < 4; ++r) {
                oacc[dt0 + 0][r] = fmaf(coefB, p0[r], oacc[dt0 + 0][r]);
                oacc[dt0 + 1][r] = fmaf(coefB, p1[r], oacc[dt0 + 1][r]);
            }
        }
    }

    // ---- epilogue: 3-round LDS tree-combine (reuses qf region) ----
    __syncthreads();                       // qf reads done everywhere
    float* epi = (float*)(smem + kQOff);   // 4 slots x 2048 floats

    if (wave >= 4) {
        #pragma unroll
        for (int dt = 0; dt < 8; ++dt)
            *(f32x4*)&epi[(wave - 4) * 2048 + dt * 256 + lane * 4] = oacc[dt];
    }
    __syncthreads();
    if (wave < 4) {
        #pragma unroll
        for (int dt = 0; dt < 8; ++dt) {
            const f32x4 o = *(const f32x4*)&epi[wave * 2048 + dt * 256 + lane * 4];
            #pragma unroll
            for (int r = 0; r < 4; ++r) oacc[dt][r] += o[r];
        }
    }
    __syncthreads();
    if (wave == 2 || wave == 3) {
        #pragma unroll
        for (int dt = 0; dt < 8; ++dt)
            *(f32x4*)&epi[(wave - 2) * 2048 + dt * 256 + lane * 4] = oacc[dt];
    }
    __syncthreads();
    if (wave < 2) {
        #pragma unroll
        for (int dt = 0; dt < 8; ++dt) {
            const f32x4 o = *(const f32x4*)&epi[wave * 2048 + dt * 256 + lane * 4];
            #pragma unroll
            for (int r = 0; r < 4; ++r) oacc[dt][r] += o[r];
        }
    }
    __syncthreads();
    if (wave == 1) {
        #pragma unroll
        for (int dt = 0; dt < 8; ++dt)
            *(f32x4*)&epi[dt * 256 + lane * 4] = oacc[dt];
    }
    __syncthreads();
    if (wave == 0) {
        float* ob = out + ((size_t)l * kHQ + h * kG + n) * kD;
        #pragma unroll
        for (int dt = 0; dt < 8; ++dt) {
            const f32x4 o = *(const f32x4*)&epi[dt * 256 + lane * 4];
            float4 val;
            #pragma unroll
            for (int r = 0; r < 4; ++r) (&val.x)[r] = oacc[dt][r] + o[r];
            *(float4*)(ob + dt * 16 + quad * 4) = val;
        }
    }
}

} // namespace

extern "C" void kernel_launch(void* const* d_in, const int* in_sizes, int n_in,
                              void* d_out, int out_size, void* d_ws, size_t ws_size,
                              hipStream_t stream)
{
    const float* q    = (const float*)d_in[0];
    const float* k    = (const float*)d_in[1];
    const float* v    = (const float*)d_in[2];
    const float* w    = (const float*)d_in[3];
    const int*   bidx = (const int*)d_in[4];
    float* out = (float*)d_out;

    uint4* kp = (uint4*)d_ws;                                   // 2 MB
    uint4* vp = (uint4*)((char*)d_ws + (size_t)kKPackN * 16);   // 2 MB

    pack_kv<<<dim3(512), dim3(256), 0, stream>>>(k, v, kp, vp);
    hsa_main<<<dim3(kLq * kH), dim3(512), 0, stream>>>(q, w, bidx, kp, vp, out);
}